// Round 8
// baseline (1581.106 us; speedup 1.0000x reference)
//
#include <hip/hip_runtime.h>
#include <cstddef>
#include <cstdint>

// ---------------- problem dims ----------------
#define L_    2
#define H_    8
#define ENC_  862
#define DM_   512
#define DFF_  2048
#define S_    512
#define P_    96
#define B_    32
#define HD_   64
#define EPAD_ 896
#define KPE_  896                  // ENC padded to K-tile multiple (64)
#define XLD_  864                  // bufXn row stride (16B-aligned; pads zeroed)
#define M1_   (B_*S_)              // 16384
#define M2_   (B_*EPAD_)           // 28672

typedef unsigned short u16;
typedef unsigned int   u32;
typedef u16   u16x8 __attribute__((ext_vector_type(8)));
typedef short s16x8 __attribute__((ext_vector_type(8)));
typedef float f32x4 __attribute__((ext_vector_type(4)));

__device__ __forceinline__ float b2f(u16 v) { return __uint_as_float(((u32)v) << 16); }
__device__ __forceinline__ u16 f2b(float f) {
    u32 u = __float_as_uint(f);
    u = (u + 0x7FFF + ((u >> 16) & 1)) >> 16;   // RNE
    return (u16)u;
}
__device__ __forceinline__ float gelu_exact(float x) {
    return 0.5f * x * (1.f + erff(x * 0.70710678118654752f));
}

// zero-fill guard gap (A-side K-overread must stay finite; cheap insurance)
__global__ __launch_bounds__(256) void zgap(u16* __restrict__ p, int n)
{
    int i = blockIdx.x * 256 + threadIdx.x;
    if (i < n) p[i] = 0;
}

// ================= MFMA GEMM: C[M][N] = A[M][K] @ BT[N][K]^T =================
// A, BT: bf16 (ws). C: bf16 ws (MODE 0-2) or f32 d_out (MODE 3).
// R: residual/bias — f32 when RF32 (device input), else bf16 ws.
// MODE 0: C = AB
// MODE 1: C = AB + R[m][n]   (ld ldR)
// MODE 2: C = gelu(AB + Rf[n])   (bias f32)
// MODE 3: outf32[(bb*96+n)*862+e] = AB + Rf[n],  m = bb*896+e, guard e<862
template<int MODE, bool RF32>
__global__ __launch_bounds__(256) void mgemm(
    const u16* __restrict__ A, int ldA,
    const u16* __restrict__ BT, int ldBT,
    void* __restrict__ Cv, int ldc,
    const void* __restrict__ R, int ldR,
    int M, int N, int KP)
{
    __shared__ u16 As[128 * 64];
    __shared__ u16 Bs[128 * 64];
    int tid = threadIdx.x;
    int l = tid & 63, w = tid >> 6;
    int m0 = blockIdx.x * 128, n0 = blockIdx.y * 128;
    int wm = (w >> 1) * 64, wn = (w & 1) * 64;
    int fr = l & 15, kb = l >> 4;

    f32x4 acc[4][4];
    #pragma unroll
    for (int i = 0; i < 4; i++)
        #pragma unroll
        for (int j = 0; j < 4; j++)
            acc[i][j] = (f32x4){0.f, 0.f, 0.f, 0.f};

    int arow = tid >> 3, acol = (tid & 7) * 8;   // 32 rows x 64 cols per chunk
    const u16* ga = A + (size_t)(m0 + arow) * ldA + acol;
    const u16* gb = BT + (size_t)(n0 + arow) * ldBT + acol;
    u16* lA = As + tid * 8;
    u16* lB = Bs + tid * 8;

    for (int kt = 0; kt < KP; kt += 64) {
        u16x8 va0 = *(const u16x8*)(ga);
        u16x8 va1 = *(const u16x8*)(ga + (size_t)32 * ldA);
        u16x8 va2 = *(const u16x8*)(ga + (size_t)64 * ldA);
        u16x8 va3 = *(const u16x8*)(ga + (size_t)96 * ldA);
        u16x8 vb0 = *(const u16x8*)(gb);
        u16x8 vb1 = *(const u16x8*)(gb + (size_t)32 * ldBT);
        u16x8 vb2 = *(const u16x8*)(gb + (size_t)64 * ldBT);
        u16x8 vb3 = *(const u16x8*)(gb + (size_t)96 * ldBT);
        ga += 64; gb += 64;
        __syncthreads();                          // prev MFMA phase done reading LDS
        *(u16x8*)(lA)          = va0;
        *(u16x8*)(lA + 2048)   = va1;
        *(u16x8*)(lA + 4096)   = va2;
        *(u16x8*)(lA + 6144)   = va3;
        *(u16x8*)(lB)          = vb0;
        *(u16x8*)(lB + 2048)   = vb1;
        *(u16x8*)(lB + 4096)   = vb2;
        *(u16x8*)(lB + 6144)   = vb3;
        __syncthreads();                          // writes visible
        #pragma unroll
        for (int ks = 0; ks < 2; ks++) {
            s16x8 af[4], bf[4];
            #pragma unroll
            for (int i = 0; i < 4; i++) {
                af[i] = *(const s16x8*)&As[(wm + i * 16 + fr) * 64 + ks * 32 + kb * 8];
                bf[i] = *(const s16x8*)&Bs[(wn + i * 16 + fr) * 64 + ks * 32 + kb * 8];
            }
            #pragma unroll
            for (int i = 0; i < 4; i++)
                #pragma unroll
                for (int j = 0; j < 4; j++)
                    acc[i][j] = __builtin_amdgcn_mfma_f32_16x16x32_bf16(af[i], bf[j], acc[i][j], 0, 0, 0);
        }
    }

    u16*   Cb = (u16*)Cv;
    float* Cf = (float*)Cv;
    const float* Rf = (const float*)R;
    const u16*   Rb = (const u16*)R;
    // epilogue: C/D layout col=lane&15, row=(lane>>4)*4+reg  [m89 HW-verified]
    #pragma unroll
    for (int i = 0; i < 4; i++) {
        int mrow = m0 + wm + i * 16 + (l >> 4) * 4;
        #pragma unroll
        for (int j = 0; j < 4; j++) {
            int ncol = n0 + wn + j * 16 + (l & 15);
            if (ncol >= N) continue;
            #pragma unroll
            for (int r = 0; r < 4; r++) {
                int m = mrow + r;
                float v = acc[i][j][r];
                if (MODE == 0) {
                    Cb[(size_t)m * ldc + ncol] = f2b(v);
                } else if (MODE == 1) {
                    v += RF32 ? Rf[(size_t)m * ldR + ncol] : b2f(Rb[(size_t)m * ldR + ncol]);
                    Cb[(size_t)m * ldc + ncol] = f2b(v);
                } else if (MODE == 2) {
                    Cb[(size_t)m * ldc + ncol] = f2b(gelu_exact(v + Rf[ncol]));
                } else {
                    int bb = m / EPAD_;
                    int e = m - bb * EPAD_;
                    if (e < ENC_)
                        Cf[((size_t)bb * P_ + ncol) * ENC_ + e] = v + Rf[ncol];   // f32 OUT
                }
            }
        }
    }
}

// ================= LayerNorm over ENC; input f32 (device) or bf16 (ws); out bf16 ld XLD_ =
template<bool XF32>
__global__ __launch_bounds__(128) void ln_k(const void* __restrict__ xv, int ldin,
                                            const float* __restrict__ w,
                                            const float* __restrict__ b,
                                            u16* __restrict__ y)
{
    int row = blockIdx.x;
    const float* xf = (const float*)xv + (size_t)row * ldin;
    const u16*   xb = (const u16*)xv + (size_t)row * ldin;
    float s = 0.f, q = 0.f;
    for (int c = threadIdx.x; c < ENC_; c += 128) {
        float v = XF32 ? xf[c] : b2f(xb[c]);
        s += v; q += v * v;
    }
    #pragma unroll
    for (int m = 1; m < 64; m <<= 1) { s += __shfl_xor(s, m, 64); q += __shfl_xor(q, m, 64); }
    __shared__ float red[4];
    int wid = threadIdx.x >> 6;
    if ((threadIdx.x & 63) == 0) { red[wid] = s; red[2 + wid] = q; }
    __syncthreads();
    s = red[0] + red[1]; q = red[2] + red[3];
    float mean = s * (1.f / ENC_);
    float var = q * (1.f / ENC_) - mean * mean;
    float rs = rsqrtf(var + 1e-5f);
    u16* yr = y + (size_t)row * XLD_;
    for (int c = threadIdx.x; c < XLD_; c += 128) {
        u16 o = 0;                                   // pad cols 862/863 -> zero
        if (c < ENC_) {
            float v = XF32 ? xf[c] : b2f(xb[c]);
            o = f2b((v - mean) * rs * w[c] + b[c]);
        }
        yr[c] = o;
    }
}

// ================= weight repacks (f32 device inputs -> bf16 ws) =================
__global__ __launch_bounds__(256) void repackT(const float* __restrict__ src, u16* __restrict__ dst,
                                               int Nsrc, int Ksrc, int KP, int total)
{
    int idx = blockIdx.x * 256 + threadIdx.x;
    if (idx >= total) return;
    int n = idx / KP, k = idx - n * KP;
    dst[idx] = (k < Ksrc && n < Nsrc) ? f2b(src[(size_t)k * Nsrc + n]) : (u16)0;
}

__global__ __launch_bounds__(256) void repack_qkvg(const float* __restrict__ wq, const float* __restrict__ wk,
                                                   const float* __restrict__ wv, const float* __restrict__ wg,
                                                   u16* __restrict__ dst)
{
    int idx = blockIdx.x * 256 + threadIdx.x;
    if (idx >= 2048 * KPE_) return;
    int n = idx / KPE_, k = idx - n * KPE_;
    u16 v = 0;
    if (k < ENC_) {
        int sec = n >> 9, c = n & 511;
        if (sec == 3) v = f2b(wg[(size_t)k * DM_ + c]);
        else {
            const float* s = (sec == 0) ? wq : (sec == 1) ? wk : wv;
            int h = c >> 6, d = c & 63;
            v = f2b(s[((size_t)h * ENC_ + k) * HD_ + d]);
        }
    }
    dst[idx] = v;
}

// ================= elementwise gates (bf16 ws) =================
__global__ __launch_bounds__(256) void gate1_k(const u16* __restrict__ QKVG,
                                               const u16* __restrict__ Yn,
                                               u16* __restrict__ out)
{
    int i = blockIdx.x * 256 + threadIdx.x;
    int row = i >> 6, col = (i & 63) * 8;
    u16x8 g = *(const u16x8*)&QKVG[(size_t)row * 2048 + 1536 + col];
    u16x8 yv = *(const u16x8*)&Yn[(size_t)row * 512 + col];
    u16x8 o;
    #pragma unroll
    for (int j = 0; j < 8; j++) {
        float gf = b2f(g[j]);
        o[j] = f2b(gf / (1.f + __expf(-gf)) * b2f(yv[j]));
    }
    *(u16x8*)&out[(size_t)row * 512 + col] = o;
}

__global__ __launch_bounds__(256) void gate2_k(const u16* __restrict__ Z, u16* __restrict__ out)
{
    int i = blockIdx.x * 256 + threadIdx.x;
    int row = i >> 6, col = (i & 63) * 8;
    u16x8 a = *(const u16x8*)&Z[(size_t)row * 1024 + col];
    u16x8 b = *(const u16x8*)&Z[(size_t)row * 1024 + 512 + col];
    u16x8 o;
    #pragma unroll
    for (int j = 0; j < 8; j++) o[j] = f2b(b2f(a[j]) * b2f(b[j]));
    *(u16x8*)&out[(size_t)row * 512 + col] = o;
}

// ================= transpose: bufF[B][S][862] bf16 -> XT[B][896][512] =================
__global__ __launch_bounds__(256) void transpose_k(const u16* __restrict__ Xf, u16* __restrict__ XT)
{
    __shared__ u16 t[64][65];
    int b = blockIdx.x, s0 = blockIdx.y * 64, e0 = blockIdx.z * 64;
    int tid = threadIdx.x;
    int sr = tid >> 2, ch = (tid & 3) * 16;
    const u16* src = Xf + ((size_t)(b * S_) + s0 + sr) * ENC_ + e0 + ch;
    #pragma unroll
    for (int i = 0; i < 16; i++)
        t[sr][ch + i] = (e0 + ch + i < ENC_) ? src[i] : (u16)0;
    __syncthreads();
    int er = tid >> 2;
    u16* dst = XT + ((size_t)b * EPAD_ + e0 + er) * 512 + s0 + ch;
    #pragma unroll
    for (int i = 0; i < 16; i++)
        dst[i] = t[ch + i][er];
}

// ================= fused retention + GroupNorm (f32 math; bf16 ws I/O; f32 gn params) ===
__global__ __launch_bounds__(256) void retention_k(const u16* __restrict__ QKVG,
                                                   const float* __restrict__ gnw,
                                                   const float* __restrict__ gnb,
                                                   u16* __restrict__ Yn)
{
    __shared__ float Qs[64][68];
    __shared__ float Ks[64][68];
    __shared__ float Vs[64][68];
    __shared__ float Ps[64][68];
    int tid = threadIdx.x;
    int st = blockIdx.x, bh = blockIdx.y;
    int b = bh >> 3, h = bh & 7;
    int s0 = st * 64;

    const float lo = -3.46573590280f;   // log(1/32)
    const float hi = -6.23832462504f;   // log(1/512)
    float gamma = 1.f - expf(lo + (float)h * ((hi - lo) * (1.f / 7.f)));
    float l2g = log2f(gamma);

    size_t rowbase = (size_t)(b * S_) * 2048 + h * 64;

    {   // Q tile -> Qs[d][r]
        int r = tid >> 2, cq = (tid & 3) * 16;
        const u16* src = QKVG + rowbase + (size_t)(s0 + r) * 2048 + cq;
        u16x8 w0 = *(const u16x8*)src;
        u16x8 w1 = *(const u16x8*)(src + 8);
        #pragma unroll
        for (int j = 0; j < 8; j++) { Qs[cq + j][r] = b2f(w0[j]); Qs[cq + 8 + j][r] = b2f(w1[j]); }
    }
    int ra = tid >> 4;
    int cb = tid & 15;
    float yacc[4][4] = {};

    for (int tt = 0; tt <= st; ++tt) {
        int t0 = tt * 64;
        __syncthreads();
        {
            int r = tid >> 2, cq = (tid & 3) * 16;
            const u16* ksrc = QKVG + rowbase + (size_t)(t0 + r) * 2048 + 512 + cq;
            const u16* vsrc = QKVG + rowbase + (size_t)(t0 + r) * 2048 + 1024 + cq;
            u16x8 k0 = *(const u16x8*)ksrc;
            u16x8 k1 = *(const u16x8*)(ksrc + 8);
            u16x8 v0 = *(const u16x8*)vsrc;
            u16x8 v1 = *(const u16x8*)(vsrc + 8);
            #pragma unroll
            for (int j = 0; j < 8; j++) {
                Ks[cq + j][r] = b2f(k0[j]); Ks[cq + 8 + j][r] = b2f(k1[j]);
                Vs[r][cq + j] = b2f(v0[j]); Vs[r][cq + 8 + j] = b2f(v1[j]);
            }
        }
        __syncthreads();

        float p[4][4] = {};
        #pragma unroll 4
        for (int d = 0; d < 64; ++d) {
            float4 qv = *(const float4*)&Qs[d][4 * ra];
            float4 kv = *(const float4*)&Ks[d][4 * cb];
            float qa[4] = {qv.x, qv.y, qv.z, qv.w};
            float ka[4] = {kv.x, kv.y, kv.z, kv.w};
            #pragma unroll
            for (int ri = 0; ri < 4; ri++)
                #pragma unroll
                for (int tj = 0; tj < 4; tj++)
                    p[ri][tj] += qa[ri] * ka[tj];
        }
        bool diag = (tt == st);
        #pragma unroll
        for (int ri = 0; ri < 4; ri++) {
            int s = s0 + 4 * ra + ri;
            #pragma unroll
            for (int tj = 0; tj < 4; tj++) {
                int t = t0 + 4 * cb + tj;
                int dd = s - t;
                float wv = (diag && dd < 0) ? 0.f : exp2f((float)dd * l2g);
                p[ri][tj] *= wv;
            }
            *(float4*)&Ps[4 * ra + ri][4 * cb] =
                make_float4(p[ri][0], p[ri][1], p[ri][2], p[ri][3]);
        }
        __syncthreads();

        #pragma unroll 4
        for (int t = 0; t < 64; ++t) {
            float4 vv = *(const float4*)&Vs[t][4 * cb];
            float va[4] = {vv.x, vv.y, vv.z, vv.w};
            float p0 = Ps[4 * ra + 0][t];
            float p1 = Ps[4 * ra + 1][t];
            float p2 = Ps[4 * ra + 2][t];
            float p3 = Ps[4 * ra + 3][t];
            #pragma unroll
            for (int dd = 0; dd < 4; dd++) {
                yacc[0][dd] += p0 * va[dd];
                yacc[1][dd] += p1 * va[dd];
                yacc[2][dd] += p2 * va[dd];
                yacc[3][dd] += p3 * va[dd];
            }
        }
    }

    #pragma unroll
    for (int ri = 0; ri < 4; ri++) {
        float s_ = yacc[ri][0] + yacc[ri][1] + yacc[ri][2] + yacc[ri][3];
        float q_ = yacc[ri][0]*yacc[ri][0] + yacc[ri][1]*yacc[ri][1]
                 + yacc[ri][2]*yacc[ri][2] + yacc[ri][3]*yacc[ri][3];
        #pragma unroll
        for (int m = 1; m < 16; m <<= 1) { s_ += __shfl_xor(s_, m, 64); q_ += __shfl_xor(q_, m, 64); }
        float mean = s_ * (1.f / 64.f);
        float var = q_ * (1.f / 64.f) - mean * mean;
        float rs = rsqrtf(var + 1e-5f);
        int srow = s0 + 4 * ra + ri;
        int c0 = h * 64 + 4 * cb;
        u32 w0 = (u32)f2b((yacc[ri][0] - mean) * rs * gnw[c0 + 0] + gnb[c0 + 0])
               | ((u32)f2b((yacc[ri][1] - mean) * rs * gnw[c0 + 1] + gnb[c0 + 1]) << 16);
        u32 w1 = (u32)f2b((yacc[ri][2] - mean) * rs * gnw[c0 + 2] + gnb[c0 + 2])
               | ((u32)f2b((yacc[ri][3] - mean) * rs * gnw[c0 + 3] + gnb[c0 + 3]) << 16);
        u32* dst = (u32*)&Yn[(size_t)(b * S_ + srow) * 512 + c0];
        dst[0] = w0; dst[1] = w1;
    }
}

// ================= launch =================
extern "C" void kernel_launch(void* const* d_in, const int* in_sizes, int n_in,
                              void* d_out, int out_size, void* d_ws, size_t ws_size,
                              hipStream_t stream)
{
    // Inputs are float32 on device; OUTPUT is float32 too (reference output dtype).
    const float* X    = (const float*)d_in[0];
    const float* wq   = (const float*)d_in[4];
    const float* wk   = (const float*)d_in[5];
    const float* wv   = (const float*)d_in[6];
    const float* wg   = (const float*)d_in[7];
    const float* wo   = (const float*)d_in[8];
    const float* gnw  = (const float*)d_in[9];
    const float* gnb  = (const float*)d_in[10];
    const float* ln1w = (const float*)d_in[11];
    const float* ln1b = (const float*)d_in[12];
    const float* ln2w = (const float*)d_in[13];
    const float* ln2b = (const float*)d_in[14];
    const float* su   = (const float*)d_in[15];
    const float* sv   = (const float*)d_in[16];
    const float* so   = (const float*)d_in[17];
    const float* tw1  = (const float*)d_in[18];
    const float* tb1  = (const float*)d_in[19];
    const float* tw2  = (const float*)d_in[20];
    const float* tb2  = (const float*)d_in[21];
    u16* ws = (u16*)d_ws;

    // ---- ws layout (u16 elements) ----
    const size_t NXE = (size_t)M1_ * ENC_;               // 14,123,008
    const size_t oA  = 0;                                // bufXn [16384][864]
    const size_t oB  = (size_t)M1_ * XLD_ + 1024;        // guard; bufQKVG [16384][2048] / bufZ
    const size_t oC  = oB + (size_t)M1_ * 2048;          // bufYn [16384][512]
    const size_t oD  = oC + (size_t)M1_ * 512;           // bufGD [16384][512]
    const size_t oE  = oD + (size_t)M1_ * 512;           // bufY [16384][862]
    const size_t oF  = oE + NXE;                         // bufF [16384][862]
    const size_t oW  = oF + NXE;                         // weights arena
    const size_t oWqkvg = oW;                                   // [2048][896]
    const size_t oWo    = oWqkvg + (size_t)2048 * KPE_;         // [896][512]
    const size_t oWsuv  = oWo + (size_t)EPAD_ * 512;            // [1024][896]
    const size_t oWso   = oWsuv + (size_t)1024 * KPE_;          // [896][512]
    const size_t oWt1   = oWso + (size_t)EPAD_ * 512;           // [2048][512]
    const size_t oWt2   = oWt1 + (size_t)2048 * 512;            // [128][2048]
    const size_t END    = oWt2 + (size_t)128 * 2048;            // ~97.7M u16 = 195 MB
    const size_t oXT = 0;                                // [32][896][512], post-layers overlay
    const size_t oT1 = (size_t)B_ * EPAD_ * 512;         // [28672][2048], post-layers overlay
    if (ws_size < END * sizeof(u16)) return;

    u16* bufXn = ws + oA;
    u16* bufQKVG = ws + oB;
    u16* bufZ = ws + oB;
    u16* bufYn = ws + oC;
    u16* bufGD = ws + oD;
    u16* bufY = ws + oE;
    u16* bufF = ws + oF;
    u16* wqkvgT = ws + oWqkvg;
    u16* woT = ws + oWo;
    u16* suvT = ws + oWsuv;
    u16* soT = ws + oWso;
    u16* tw1T = ws + oWt1;
    u16* tw2T = ws + oWt2;
    u16* XT = ws + oXT;
    u16* T1 = ws + oT1;

    dim3 blk(256);
    const size_t NW = (size_t)ENC_ * DM_;   // per-layer weight stride (= H*ENC*HD)

    zgap<<<dim3(4), blk, 0, stream>>>(ws + (size_t)M1_ * XLD_, 1024);

    for (int l = 0; l < L_; ++l) {
        repack_qkvg<<<dim3((2048 * KPE_ + 255) / 256), blk, 0, stream>>>(
            wq + l * NW, wk + l * NW, wv + l * NW, wg + l * NW, wqkvgT);
        repackT<<<dim3((EPAD_ * 512 + 255) / 256), blk, 0, stream>>>(wo + l * NW, woT, ENC_, DM_, 512, EPAD_ * 512);
        repackT<<<dim3((512 * KPE_ + 255) / 256), blk, 0, stream>>>(su + l * NW, suvT, DM_, ENC_, KPE_, 512 * KPE_);
        repackT<<<dim3((512 * KPE_ + 255) / 256), blk, 0, stream>>>(sv + l * NW, suvT + (size_t)512 * KPE_, DM_, ENC_, KPE_, 512 * KPE_);
        repackT<<<dim3((EPAD_ * 512 + 255) / 256), blk, 0, stream>>>(so + l * NW, soT, ENC_, DM_, 512, EPAD_ * 512);

        if (l == 0)
            ln_k<true ><<<dim3(M1_), dim3(128), 0, stream>>>(X,    ENC_, ln1w + l * ENC_, ln1b + l * ENC_, bufXn);
        else
            ln_k<false><<<dim3(M1_), dim3(128), 0, stream>>>(bufF, ENC_, ln1w + l * ENC_, ln1b + l * ENC_, bufXn);

        mgemm<0, false><<<dim3(M1_ / 128, 16), blk, 0, stream>>>(bufXn, XLD_, wqkvgT, KPE_,
                                                                 bufQKVG, 2048, nullptr, 0, M1_, 2048, KPE_);

        retention_k<<<dim3(S_ / 64, B_ * H_), blk, 0, stream>>>(bufQKVG, gnw + l * DM_, gnb + l * DM_, bufYn);

        gate1_k<<<dim3(M1_ * 64 / 256), blk, 0, stream>>>(bufQKVG, bufYn, bufGD);

        if (l == 0)
            mgemm<1, true ><<<dim3(M1_ / 128, 7), blk, 0, stream>>>(bufGD, 512, woT, 512,
                                                                    bufY, ENC_, X, ENC_, M1_, ENC_, 512);
        else
            mgemm<1, false><<<dim3(M1_ / 128, 7), blk, 0, stream>>>(bufGD, 512, woT, 512,
                                                                    bufY, ENC_, bufF, ENC_, M1_, ENC_, 512);

        ln_k<false><<<dim3(M1_), dim3(128), 0, stream>>>(bufY, ENC_, ln2w + l * ENC_, ln2b + l * ENC_, bufXn);

        mgemm<0, false><<<dim3(M1_ / 128, 8), blk, 0, stream>>>(bufXn, XLD_, suvT, KPE_,
                                                                bufZ, 1024, nullptr, 0, M1_, 1024, KPE_);

        gate2_k<<<dim3(M1_ * 64 / 256), blk, 0, stream>>>(bufZ, bufGD);

        mgemm<1, false><<<dim3(M1_ / 128, 7), blk, 0, stream>>>(bufGD, 512, soT, 512,
                                                                bufF, ENC_, bufY, ENC_, M1_, ENC_, 512);
    }

    // temporal projection
    repackT<<<dim3((2048 * 512 + 255) / 256), blk, 0, stream>>>(tw1, tw1T, DFF_, S_, 512, 2048 * 512);
    repackT<<<dim3((128 * 2048 + 255) / 256), blk, 0, stream>>>(tw2, tw2T, P_, DFF_, 2048, 128 * 2048);

    transpose_k<<<dim3(B_, S_ / 64, EPAD_ / 64), blk, 0, stream>>>(bufF, XT);

    mgemm<2, false><<<dim3(M2_ / 128, 16), blk, 0, stream>>>(XT, 512, tw1T, 512,
                                                             T1, DFF_, tb1, 0, M2_, DFF_, 512);
    mgemm<3, false><<<dim3(M2_ / 128, 1), blk, 0, stream>>>(T1, DFF_, tw2T, 2048,
                                                            d_out, 0, tb2, 0, M2_, P_, 2048);
}

// Round 10
// 1173.748 us; speedup vs baseline: 1.3471x; 1.3471x over previous
//
#include <hip/hip_runtime.h>
#include <cstddef>
#include <cstdint>

// ---------------- problem dims ----------------
#define L_    2
#define H_    8
#define ENC_  862
#define DM_   512
#define DFF_  2048
#define S_    512
#define P_    96
#define B_    32
#define HD_   64
#define EPAD_ 896
#define KPE_  896                  // ENC padded to K-tile multiple (64)
#define XLD_  864                  // bufXn row stride (16B-aligned; pads zeroed)
#define M1_   (B_*S_)              // 16384
#define M2_   (B_*EPAD_)           // 28672

typedef unsigned short u16;
typedef unsigned int   u32;
typedef u16   u16x8 __attribute__((ext_vector_type(8)));
typedef short s16x8 __attribute__((ext_vector_type(8)));
typedef float f32x4 __attribute__((ext_vector_type(4)));

__device__ __forceinline__ float b2f(u16 v) { return __uint_as_float(((u32)v) << 16); }
__device__ __forceinline__ u16 f2b(float f) {
    u32 u = __float_as_uint(f);
    u = (u + 0x7FFF + ((u >> 16) & 1)) >> 16;   // RNE
    return (u16)u;
}
__device__ __forceinline__ float gelu_exact(float x) {
    return 0.5f * x * (1.f + erff(x * 0.70710678118654752f));
}

// ---------------- async global->LDS, 16B per lane (m97 pattern) ----------------
typedef __attribute__((address_space(1))) const void gas_void;
typedef __attribute__((address_space(3))) void sas_void;
__device__ __forceinline__ void gload16(const u16* g, u16* l) {
    __builtin_amdgcn_global_load_lds((gas_void*)g, (sas_void*)l, 16, 0, 0);
}

// zero-fill guard gap (A-side K-overread must stay finite)
__global__ __launch_bounds__(256) void zgap(u16* __restrict__ p, int n)
{
    int i = blockIdx.x * 256 + threadIdx.x;
    if (i < n) p[i] = 0;
}

// ================= MFMA GEMM: C[M][N] = A[M][K] @ BT[N][K]^T =================
// global_load_lds staging (all sources 16B-aligned: XLD_/ws strides are 8-elem mults).
// MODE 0: C = AB ; MODE 1: C = AB + R[m][n] ; MODE 2: C = gelu(AB + Rf[n])
// MODE 3: outf32[(bb*96+n)*862+e] = AB + Rf[n],  m = bb*896+e, guard e<862
template<int MODE, bool RF32>
__global__ __launch_bounds__(256) void mgemm(
    const u16* __restrict__ A, int ldA,
    const u16* __restrict__ BT, int ldBT,
    void* __restrict__ Cv, int ldc,
    const void* __restrict__ R, int ldR,
    int M, int N, int KP)
{
    __shared__ u16 As[128 * 64];
    __shared__ u16 Bs[128 * 64];
    int tid = threadIdx.x;
    int l = tid & 63, w = tid >> 6;
    int m0 = blockIdx.x * 128, n0 = blockIdx.y * 128;
    int wm = (w >> 1) * 64, wn = (w & 1) * 64;
    int fr = l & 15, kb = l >> 4;

    f32x4 acc[4][4];
    #pragma unroll
    for (int i = 0; i < 4; i++)
        #pragma unroll
        for (int j = 0; j < 4; j++)
            acc[i][j] = (f32x4){0.f, 0.f, 0.f, 0.f};

    int arow = tid >> 3, acol = (tid & 7) * 8;   // 32 rows x 64 cols per chunk
    const u16* ga = A + (size_t)(m0 + arow) * ldA + acol;
    const u16* gb = BT + (size_t)(n0 + arow) * ldBT + acol;
    u16* lA = As + tid * 8;                      // wave base + lane*16B  (DMA layout)
    u16* lB = Bs + tid * 8;

    for (int kt = 0; kt < KP; kt += 64) {
        #pragma unroll
        for (int c = 0; c < 4; c++) {
            gload16(ga + (size_t)(c * 32) * ldA, lA + c * 2048);
            gload16(gb + (size_t)(c * 32) * ldBT, lB + c * 2048);
        }
        ga += 64; gb += 64;
        __syncthreads();   // compiler drains vmcnt(0) before s_barrier -> DMA complete
        #pragma unroll
        for (int ks = 0; ks < 2; ks++) {
            s16x8 af[4], bf[4];
            #pragma unroll
            for (int i = 0; i < 4; i++) {
                af[i] = *(const s16x8*)&As[(wm + i * 16 + fr) * 64 + ks * 32 + kb * 8];
                bf[i] = *(const s16x8*)&Bs[(wn + i * 16 + fr) * 64 + ks * 32 + kb * 8];
            }
            #pragma unroll
            for (int i = 0; i < 4; i++)
                #pragma unroll
                for (int j = 0; j < 4; j++)
                    acc[i][j] = __builtin_amdgcn_mfma_f32_16x16x32_bf16(af[i], bf[j], acc[i][j], 0, 0, 0);
        }
        __syncthreads();   // all reads done before next tile's DMA overwrites
    }

    u16*   Cb = (u16*)Cv;
    float* Cf = (float*)Cv;
    const float* Rf = (const float*)R;
    const u16*   Rb = (const u16*)R;
    // epilogue: C/D layout col=lane&15, row=(lane>>4)*4+reg  [m89 HW-verified]
    #pragma unroll
    for (int i = 0; i < 4; i++) {
        int mrow = m0 + wm + i * 16 + (l >> 4) * 4;
        #pragma unroll
        for (int j = 0; j < 4; j++) {
            int ncol = n0 + wn + j * 16 + (l & 15);
            if (ncol >= N) continue;
            #pragma unroll
            for (int r = 0; r < 4; r++) {
                int m = mrow + r;
                float v = acc[i][j][r];
                if (MODE == 0) {
                    Cb[(size_t)m * ldc + ncol] = f2b(v);
                } else if (MODE == 1) {
                    v += RF32 ? Rf[(size_t)m * ldR + ncol] : b2f(Rb[(size_t)m * ldR + ncol]);
                    Cb[(size_t)m * ldc + ncol] = f2b(v);
                } else if (MODE == 2) {
                    Cb[(size_t)m * ldc + ncol] = f2b(gelu_exact(v + Rf[ncol]));
                } else {
                    int bb = m / EPAD_;
                    int e = m - bb * EPAD_;
                    if (e < ENC_)
                        Cf[((size_t)bb * P_ + ncol) * ENC_ + e] = v + Rf[ncol];   // f32 OUT
                }
            }
        }
    }
}

// ================= LayerNorm over ENC; input f32 (device) or bf16 (ws); out bf16 ld XLD_ =
template<bool XF32>
__global__ __launch_bounds__(128) void ln_k(const void* __restrict__ xv, int ldin,
                                            const float* __restrict__ w,
                                            const float* __restrict__ b,
                                            u16* __restrict__ y)
{
    int row = blockIdx.x;
    const float* xf = (const float*)xv + (size_t)row * ldin;
    const u16*   xb = (const u16*)xv + (size_t)row * ldin;
    float s = 0.f, q = 0.f;
    for (int c = threadIdx.x; c < ENC_; c += 128) {
        float v = XF32 ? xf[c] : b2f(xb[c]);
        s += v; q += v * v;
    }
    #pragma unroll
    for (int m = 1; m < 64; m <<= 1) { s += __shfl_xor(s, m, 64); q += __shfl_xor(q, m, 64); }
    __shared__ float red[4];
    int wid = threadIdx.x >> 6;
    if ((threadIdx.x & 63) == 0) { red[wid] = s; red[2 + wid] = q; }
    __syncthreads();
    s = red[0] + red[1]; q = red[2] + red[3];
    float mean = s * (1.f / ENC_);
    float var = q * (1.f / ENC_) - mean * mean;
    float rs = rsqrtf(var + 1e-5f);
    u16* yr = y + (size_t)row * XLD_;
    for (int c = threadIdx.x; c < XLD_; c += 128) {
        u16 o = 0;                                   // pad cols 862/863 -> zero
        if (c < ENC_) {
            float v = XF32 ? xf[c] : b2f(xb[c]);
            o = f2b((v - mean) * rs * w[c] + b[c]);
        }
        yr[c] = o;
    }
}

// ================= weight repacks (f32 device inputs -> bf16 ws) =================
__global__ __launch_bounds__(256) void repackT(const float* __restrict__ src, u16* __restrict__ dst,
                                               int Nsrc, int Ksrc, int KP, int total)
{
    int idx = blockIdx.x * 256 + threadIdx.x;
    if (idx >= total) return;
    int n = idx / KP, k = idx - n * KP;
    dst[idx] = (k < Ksrc && n < Nsrc) ? f2b(src[(size_t)k * Nsrc + n]) : (u16)0;
}

__global__ __launch_bounds__(256) void repack_qkvg(const float* __restrict__ wq, const float* __restrict__ wk,
                                                   const float* __restrict__ wv, const float* __restrict__ wg,
                                                   u16* __restrict__ dst)
{
    int idx = blockIdx.x * 256 + threadIdx.x;
    if (idx >= 2048 * KPE_) return;
    int n = idx / KPE_, k = idx - n * KPE_;
    u16 v = 0;
    if (k < ENC_) {
        int sec = n >> 9, c = n & 511;
        if (sec == 3) v = f2b(wg[(size_t)k * DM_ + c]);
        else {
            const float* s = (sec == 0) ? wq : (sec == 1) ? wk : wv;
            int h = c >> 6, d = c & 63;
            v = f2b(s[((size_t)h * ENC_ + k) * HD_ + d]);
        }
    }
    dst[idx] = v;
}

// ================= elementwise gates (bf16 ws) =================
__global__ __launch_bounds__(256) void gate1_k(const u16* __restrict__ QKVG,
                                               const u16* __restrict__ Yn,
                                               u16* __restrict__ out)
{
    int i = blockIdx.x * 256 + threadIdx.x;
    int row = i >> 6, col = (i & 63) * 8;
    u16x8 g = *(const u16x8*)&QKVG[(size_t)row * 2048 + 1536 + col];
    u16x8 yv = *(const u16x8*)&Yn[(size_t)row * 512 + col];
    u16x8 o;
    #pragma unroll
    for (int j = 0; j < 8; j++) {
        float gf = b2f(g[j]);
        o[j] = f2b(gf / (1.f + __expf(-gf)) * b2f(yv[j]));
    }
    *(u16x8*)&out[(size_t)row * 512 + col] = o;
}

__global__ __launch_bounds__(256) void gate2_k(const u16* __restrict__ Z, u16* __restrict__ out)
{
    int i = blockIdx.x * 256 + threadIdx.x;
    int row = i >> 6, col = (i & 63) * 8;
    u16x8 a = *(const u16x8*)&Z[(size_t)row * 1024 + col];
    u16x8 b = *(const u16x8*)&Z[(size_t)row * 1024 + 512 + col];
    u16x8 o;
    #pragma unroll
    for (int j = 0; j < 8; j++) o[j] = f2b(b2f(a[j]) * b2f(b[j]));
    *(u16x8*)&out[(size_t)row * 512 + col] = o;
}

// ================= transpose: bufF[B][S][862] bf16 -> XT[B][896][512] =================
__global__ __launch_bounds__(256) void transpose_k(const u16* __restrict__ Xf, u16* __restrict__ XT)
{
    __shared__ u16 t[64][65];
    int b = blockIdx.x, s0 = blockIdx.y * 64, e0 = blockIdx.z * 64;
    int tid = threadIdx.x;
    int sr = tid >> 2, ch = (tid & 3) * 16;
    const u16* src = Xf + ((size_t)(b * S_) + s0 + sr) * ENC_ + e0 + ch;
    #pragma unroll
    for (int i = 0; i < 16; i++)
        t[sr][ch + i] = (e0 + ch + i < ENC_) ? src[i] : (u16)0;
    __syncthreads();
    int er = tid >> 2;
    u16* dst = XT + ((size_t)b * EPAD_ + e0 + er) * 512 + s0 + ch;
    #pragma unroll
    for (int i = 0; i < 16; i++)
        dst[i] = t[ch + i][er];
}

// ================= MFMA retention + GroupNorm =================
// grid (S/64, B*H), 256 thr (4 waves). Decay folded into operands:
// gamma^(s-t) = (gamma^(s-s0) Q[s]) . (gamma^(s0-t) K[t]); only diag tile masks s<t.
__global__ __launch_bounds__(256) void retention_k(const u16* __restrict__ QKVG,
                                                   const float* __restrict__ gnw,
                                                   const float* __restrict__ gnb,
                                                   u16* __restrict__ Yn)
{
    __shared__ u16 Ks[64 * 72];   // K' rows [t][d], stride 72
    __shared__ u16 Vt[64 * 72];   // V^T [d][t], stride 72
    __shared__ u16 Pl[64 * 72];   // P bf16 [s_rel][t], stride 72 (per-wave rows)
    int tid = threadIdx.x;
    int l = tid & 63, w = tid >> 6;
    int g = l >> 4, fr = l & 15;
    int st = blockIdx.x, bh = blockIdx.y;
    int b = bh >> 3, h = bh & 7;
    int s0 = st * 64;

    const float lo = -3.46573590280f;   // log(1/32)
    const float hi = -6.23832462504f;   // log(1/512)
    float gamma = 1.f - expf(lo + (float)h * ((hi - lo) * (1.f / 7.f)));
    float l2g = log2f(gamma);

    size_t qbase = (size_t)(b * S_) * 2048 + h * 64;

    // ---- Q fragments in registers, scaled by gamma^(s - s0) ----
    int qs_rel = w * 16 + fr;                      // A-frag row = lane&15
    float qscale = exp2f((float)qs_rel * l2g);
    s16x8 qa[2];
    {
        const u16* qsrc = QKVG + qbase + (size_t)(s0 + qs_rel) * 2048;
        #pragma unroll
        for (int ks = 0; ks < 2; ks++) {
            u16x8 raw = *(const u16x8*)(qsrc + ks * 32 + g * 8);
            s16x8 sc;
            #pragma unroll
            for (int e = 0; e < 8; e++) sc[e] = (short)f2b(b2f(raw[e]) * qscale);
            qa[ks] = sc;
        }
    }

    f32x4 accy[4];
    #pragma unroll
    for (int jj = 0; jj < 4; jj++) accy[jj] = (f32x4){0.f, 0.f, 0.f, 0.f};

    int tv = tid >> 2, dv0 = (tid & 3) * 16;       // staging: row tv, 16 cols at dv0

    for (int tt = 0; tt <= st; ++tt) {
        int t0 = tt * 64;
        __syncthreads();                            // prev tile reads done
        {   // stage K' (scaled) row-major + V transposed
            float kscale = exp2f((float)(s0 - (t0 + tv)) * l2g);
            const u16* ksrc = QKVG + qbase + (size_t)(t0 + tv) * 2048 + 512 + dv0;
            const u16* vsrc = QKVG + qbase + (size_t)(t0 + tv) * 2048 + 1024 + dv0;
            u16x8 k0 = *(const u16x8*)ksrc;
            u16x8 k1 = *(const u16x8*)(ksrc + 8);
            s16x8 o0, o1;
            #pragma unroll
            for (int e = 0; e < 8; e++) {
                o0[e] = (short)f2b(b2f(k0[e]) * kscale);
                o1[e] = (short)f2b(b2f(k1[e]) * kscale);
            }
            *(s16x8*)&Ks[tv * 72 + dv0]     = o0;
            *(s16x8*)&Ks[tv * 72 + dv0 + 8] = o1;
            u16x8 v0 = *(const u16x8*)vsrc;
            u16x8 v1 = *(const u16x8*)(vsrc + 8);
            #pragma unroll
            for (int e = 0; e < 8; e++) {
                Vt[(dv0 + e) * 72 + tv]     = v0[e];
                Vt[(dv0 + 8 + e) * 72 + tv] = v1[e];
            }
        }
        __syncthreads();

        // ---- S = Q'K'^T (per wave: 16 rows x 64 t) ----
        f32x4 ps[4];
        #pragma unroll
        for (int j = 0; j < 4; j++) ps[j] = (f32x4){0.f, 0.f, 0.f, 0.f};
        #pragma unroll
        for (int ks = 0; ks < 2; ks++) {
            #pragma unroll
            for (int j = 0; j < 4; j++) {
                s16x8 kf = *(const s16x8*)&Ks[(j * 16 + fr) * 72 + ks * 32 + g * 8];
                ps[j] = __builtin_amdgcn_mfma_f32_16x16x32_bf16(qa[ks], kf, ps[j], 0, 0, 0);
            }
        }
        // ---- mask (diag only) + write P to LDS (bf16) ----
        bool diag = (tt == st);
        #pragma unroll
        for (int j = 0; j < 4; j++) {
            #pragma unroll
            for (int r = 0; r < 4; r++) {
                int srel = w * 16 + g * 4 + r;      // C/D row
                int tloc = j * 16 + fr;             // C/D col
                float p = ps[j][r];
                if (diag && (srel < tloc)) p = 0.f;
                Pl[srel * 72 + tloc] = f2b(p);
            }
        }
        // ---- Y += P V  (A = P rows, B = V^T rows) ----
        s16x8 pa0 = *(const s16x8*)&Pl[(w * 16 + fr) * 72 + g * 8];
        s16x8 pa1 = *(const s16x8*)&Pl[(w * 16 + fr) * 72 + 32 + g * 8];
        #pragma unroll
        for (int jj = 0; jj < 4; jj++) {
            s16x8 vb0 = *(const s16x8*)&Vt[(jj * 16 + fr) * 72 + g * 8];
            s16x8 vb1 = *(const s16x8*)&Vt[(jj * 16 + fr) * 72 + 32 + g * 8];
            accy[jj] = __builtin_amdgcn_mfma_f32_16x16x32_bf16(pa0, vb0, accy[jj], 0, 0, 0);
            accy[jj] = __builtin_amdgcn_mfma_f32_16x16x32_bf16(pa1, vb1, accy[jj], 0, 0, 0);
        }
    }

    // ---- GroupNorm over d=64 per row; row = w*16 + g*4 + r, cols jj*16+fr ----
    #pragma unroll
    for (int r = 0; r < 4; r++) {
        float s_ = accy[0][r] + accy[1][r] + accy[2][r] + accy[3][r];
        float q_ = accy[0][r]*accy[0][r] + accy[1][r]*accy[1][r]
                 + accy[2][r]*accy[2][r] + accy[3][r]*accy[3][r];
        #pragma unroll
        for (int m = 1; m < 16; m <<= 1) { s_ += __shfl_xor(s_, m, 64); q_ += __shfl_xor(q_, m, 64); }
        float mean = s_ * (1.f / 64.f);
        float var = q_ * (1.f / 64.f) - mean * mean;
        float rs = rsqrtf(var + 1e-5f);
        int srow = s0 + w * 16 + g * 4 + r;
        #pragma unroll
        for (int jj = 0; jj < 4; jj++) {
            int c0 = h * 64 + jj * 16 + fr;
            Yn[(size_t)(b * S_ + srow) * 512 + c0] =
                f2b((accy[jj][r] - mean) * rs * gnw[c0] + gnb[c0]);
        }
    }
}

// ================= launch =================
extern "C" void kernel_launch(void* const* d_in, const int* in_sizes, int n_in,
                              void* d_out, int out_size, void* d_ws, size_t ws_size,
                              hipStream_t stream)
{
    const float* X    = (const float*)d_in[0];
    const float* wq   = (const float*)d_in[4];
    const float* wk   = (const float*)d_in[5];
    const float* wv   = (const float*)d_in[6];
    const float* wg   = (const float*)d_in[7];
    const float* wo   = (const float*)d_in[8];
    const float* gnw  = (const float*)d_in[9];
    const float* gnb  = (const float*)d_in[10];
    const float* ln1w = (const float*)d_in[11];
    const float* ln1b = (const float*)d_in[12];
    const float* ln2w = (const float*)d_in[13];
    const float* ln2b = (const float*)d_in[14];
    const float* su   = (const float*)d_in[15];
    const float* sv   = (const float*)d_in[16];
    const float* so   = (const float*)d_in[17];
    const float* tw1  = (const float*)d_in[18];
    const float* tb1  = (const float*)d_in[19];
    const float* tw2  = (const float*)d_in[20];
    const float* tb2  = (const float*)d_in[21];
    u16* ws = (u16*)d_ws;

    // ---- ws layout (u16 elements) ----
    const size_t NXE = (size_t)M1_ * ENC_;               // 14,123,008
    const size_t oA  = 0;                                // bufXn [16384][864]
    const size_t oB  = (size_t)M1_ * XLD_ + 1024;        // guard; bufQKVG [16384][2048] / bufZ
    const size_t oC  = oB + (size_t)M1_ * 2048;          // bufYn [16384][512]
    const size_t oD  = oC + (size_t)M1_ * 512;           // bufGD [16384][512]
    const size_t oE  = oD + (size_t)M1_ * 512;           // bufY [16384][862]
    const size_t oF  = oE + NXE;                         // bufF [16384][862]
    const size_t oW  = oF + NXE;                         // weights arena
    const size_t oWqkvg = oW;                                   // [2048][896]
    const size_t oWo    = oWqkvg + (size_t)2048 * KPE_;         // [896][512]
    const size_t oWsuv  = oWo + (size_t)EPAD_ * 512;            // [1024][896]
    const size_t oWso   = oWsuv + (size_t)1024 * KPE_;          // [896][512]
    const size_t oWt1   = oWso + (size_t)EPAD_ * 512;           // [2048][512]
    const size_t oWt2   = oWt1 + (size_t)2048 * 512;            // [128][2048]
    const size_t END    = oWt2 + (size_t)128 * 2048;            // ~97.7M u16 = 195 MB
    const size_t oXT = 0;                                // post-layers overlay
    const size_t oT1 = (size_t)B_ * EPAD_ * 512;         // post-layers overlay
    if (ws_size < END * sizeof(u16)) return;

    u16* bufXn = ws + oA;
    u16* bufQKVG = ws + oB;
    u16* bufZ = ws + oB;
    u16* bufYn = ws + oC;
    u16* bufGD = ws + oD;
    u16* bufY = ws + oE;
    u16* bufF = ws + oF;
    u16* wqkvgT = ws + oWqkvg;
    u16* woT = ws + oWo;
    u16* suvT = ws + oWsuv;
    u16* soT = ws + oWso;
    u16* tw1T = ws + oWt1;
    u16* tw2T = ws + oWt2;
    u16* XT = ws + oXT;
    u16* T1 = ws + oT1;

    dim3 blk(256);
    const size_t NW = (size_t)ENC_ * DM_;

    zgap<<<dim3(4), blk, 0, stream>>>(ws + (size_t)M1_ * XLD_, 1024);

    for (int l = 0; l < L_; ++l) {
        repack_qkvg<<<dim3((2048 * KPE_ + 255) / 256), blk, 0, stream>>>(
            wq + l * NW, wk + l * NW, wv + l * NW, wg + l * NW, wqkvgT);
        repackT<<<dim3((EPAD_ * 512 + 255) / 256), blk, 0, stream>>>(wo + l * NW, woT, ENC_, DM_, 512, EPAD_ * 512);
        repackT<<<dim3((512 * KPE_ + 255) / 256), blk, 0, stream>>>(su + l * NW, suvT, DM_, ENC_, KPE_, 512 * KPE_);
        repackT<<<dim3((512 * KPE_ + 255) / 256), blk, 0, stream>>>(sv + l * NW, suvT + (size_t)512 * KPE_, DM_, ENC_, KPE_, 512 * KPE_);
        repackT<<<dim3((EPAD_ * 512 + 255) / 256), blk, 0, stream>>>(so + l * NW, soT, ENC_, DM_, 512, EPAD_ * 512);

        if (l == 0)
            ln_k<true ><<<dim3(M1_), dim3(128), 0, stream>>>(X,    ENC_, ln1w + l * ENC_, ln1b + l * ENC_, bufXn);
        else
            ln_k<false><<<dim3(M1_), dim3(128), 0, stream>>>(bufF, ENC_, ln1w + l * ENC_, ln1b + l * ENC_, bufXn);

        mgemm<0, false><<<dim3(M1_ / 128, 16), blk, 0, stream>>>(bufXn, XLD_, wqkvgT, KPE_,
                                                                 bufQKVG, 2048, nullptr, 0, M1_, 2048, KPE_);

        retention_k<<<dim3(S_ / 64, B_ * H_), blk, 0, stream>>>(bufQKVG, gnw + l * DM_, gnb + l * DM_, bufYn);

        gate1_k<<<dim3(M1_ * 64 / 256), blk, 0, stream>>>(bufQKVG, bufYn, bufGD);

        if (l == 0)
            mgemm<1, true ><<<dim3(M1_ / 128, 7), blk, 0, stream>>>(bufGD, 512, woT, 512,
                                                                    bufY, ENC_, X, ENC_, M1_, ENC_, 512);
        else
            mgemm<1, false><<<dim3(M1_ / 128, 7), blk, 0, stream>>>(bufGD, 512, woT, 512,
                                                                    bufY, ENC_, bufF, ENC_, M1_, ENC_, 512);

        ln_k<false><<<dim3(M1_), dim3(128), 0, stream>>>(bufY, ENC_, ln2w + l * ENC_, ln2b + l * ENC_, bufXn);

        mgemm<0, false><<<dim3(M1_ / 128, 8), blk, 0, stream>>>(bufXn, XLD_, suvT, KPE_,
                                                                bufZ, 1024, nullptr, 0, M1_, 1024, KPE_);

        gate2_k<<<dim3(M1_ * 64 / 256), blk, 0, stream>>>(bufZ, bufGD);

        mgemm<1, false><<<dim3(M1_ / 128, 7), blk, 0, stream>>>(bufGD, 512, soT, 512,
                                                                bufF, ENC_, bufY, ENC_, M1_, ENC_, 512);
    }

    // temporal projection
    repackT<<<dim3((2048 * 512 + 255) / 256), blk, 0, stream>>>(tw1, tw1T, DFF_, S_, 512, 2048 * 512);
    repackT<<<dim3((128 * 2048 + 255) / 256), blk, 0, stream>>>(tw2, tw2T, P_, DFF_, 2048, 128 * 2048);

    transpose_k<<<dim3(B_, S_ / 64, EPAD_ / 64), blk, 0, stream>>>(bufF, XT);

    mgemm<2, false><<<dim3(M2_ / 128, 16), blk, 0, stream>>>(XT, 512, tw1T, 512,
                                                             T1, DFF_, tb1, 0, M2_, DFF_, 512);
    mgemm<3, false><<<dim3(M2_ / 128, 1), blk, 0, stream>>>(T1, DFF_, tw2T, 2048,
                                                            d_out, 0, tb2, 0, M2_, P_, 2048);
}

// Round 12
// 1167.586 us; speedup vs baseline: 1.3542x; 1.0053x over previous
//
#include <hip/hip_runtime.h>
#include <cstddef>
#include <cstdint>

// ---------------- problem dims ----------------
#define L_    2
#define H_    8
#define ENC_  862
#define DM_   512
#define DFF_  2048
#define S_    512
#define P_    96
#define B_    32
#define HD_   64
#define EPAD_ 896
#define KPE_  896                  // ENC padded to K-tile multiple (64)
#define XLD_  864                  // bufXn row stride (16B-aligned; pads zeroed)
#define M1_   (B_*S_)              // 16384
#define M2_   (B_*EPAD_)           // 28672

typedef unsigned short u16;
typedef unsigned int   u32;
typedef u16   u16x8 __attribute__((ext_vector_type(8)));
typedef short s16x8 __attribute__((ext_vector_type(8)));
typedef float f32x4 __attribute__((ext_vector_type(4)));

__device__ __forceinline__ float b2f(u16 v) { return __uint_as_float(((u32)v) << 16); }
__device__ __forceinline__ u16 f2b(float f) {
    u32 u = __float_as_uint(f);
    u = (u + 0x7FFF + ((u >> 16) & 1)) >> 16;   // RNE
    return (u16)u;
}
__device__ __forceinline__ float gelu_exact(float x) {
    return 0.5f * x * (1.f + erff(x * 0.70710678118654752f));
}

// ---------------- async global->LDS, 16B per lane (m97 pattern) ----------------
typedef __attribute__((address_space(1))) const void gas_void;
typedef __attribute__((address_space(3))) void sas_void;
__device__ __forceinline__ void gload16(const u16* g, u16* l) {
    __builtin_amdgcn_global_load_lds((gas_void*)g, (sas_void*)l, 16, 0, 0);
}

// zero-fill guard gap (A-side K-overread must stay finite)
__global__ __launch_bounds__(256) void zgap(u16* __restrict__ p, int n)
{
    int i = blockIdx.x * 256 + threadIdx.x;
    if (i < n) p[i] = 0;
}

// ================= MFMA GEMM: C[M][N] = A[M][K] @ BT[N][K]^T =================
// Double-buffered LDS (T3-minimum): stage(t+1 -> buf^1) issued BEFORE compute(t),
// single barrier per K-step (drains vmcnt -> next buffer landed, reads of cur done).
// MODE 0: C = AB ; MODE 1: C = AB + R[m][n] ; MODE 2: C = gelu(AB + Rf[n])
// MODE 3: outf32[(bb*96+n)*862+e] = AB + Rf[n],  m = bb*896+e, guard e<862
template<int MODE, bool RF32>
__global__ __launch_bounds__(256) void mgemm(
    const u16* __restrict__ A, int ldA,
    const u16* __restrict__ BT, int ldBT,
    void* __restrict__ Cv, int ldc,
    const void* __restrict__ R, int ldR,
    int M, int N, int KP)
{
    __shared__ u16 As[2][128 * 64];
    __shared__ u16 Bs[2][128 * 64];
    int tid = threadIdx.x;
    int l = tid & 63, w = tid >> 6;
    int m0 = blockIdx.x * 128, n0 = blockIdx.y * 128;
    int wm = (w >> 1) * 64, wn = (w & 1) * 64;
    int fr = l & 15, kb = l >> 4;

    f32x4 acc[4][4];
    #pragma unroll
    for (int i = 0; i < 4; i++)
        #pragma unroll
        for (int j = 0; j < 4; j++)
            acc[i][j] = (f32x4){0.f, 0.f, 0.f, 0.f};

    int arow = tid >> 3, acol = (tid & 7) * 8;   // 32 rows x 64 cols per chunk
    const u16* gaBase = A + (size_t)(m0 + arow) * ldA + acol;
    const u16* gbBase = BT + (size_t)(n0 + arow) * ldBT + acol;

    auto stage = [&](int kofs, int bufi) {
        const u16* ga = gaBase + kofs;
        const u16* gb = gbBase + kofs;
        u16* lA = As[bufi] + tid * 8;
        u16* lB = Bs[bufi] + tid * 8;
        #pragma unroll
        for (int c = 0; c < 4; c++) {
            gload16(ga + (size_t)(c * 32) * ldA, lA + c * 2048);
            gload16(gb + (size_t)(c * 32) * ldBT, lB + c * 2048);
        }
    };

    stage(0, 0);
    __syncthreads();                              // drain: buf0 landed
    int nt = KP >> 6;
    for (int t = 0; t < nt; ++t) {
        int cur = t & 1;
        if (t + 1 < nt) stage((t + 1) << 6, cur ^ 1);   // async prefetch, no wait
        #pragma unroll
        for (int ks = 0; ks < 2; ks++) {
            s16x8 af[4], bf[4];
            #pragma unroll
            for (int i = 0; i < 4; i++) {
                af[i] = *(const s16x8*)&As[cur][(wm + i * 16 + fr) * 64 + ks * 32 + kb * 8];
                bf[i] = *(const s16x8*)&Bs[cur][(wn + i * 16 + fr) * 64 + ks * 32 + kb * 8];
            }
            #pragma unroll
            for (int i = 0; i < 4; i++)
                #pragma unroll
                for (int j = 0; j < 4; j++)
                    acc[i][j] = __builtin_amdgcn_mfma_f32_16x16x32_bf16(af[i], bf[j], acc[i][j], 0, 0, 0);
        }
        __syncthreads();   // drains vmcnt(0)+lgkm: prefetch landed, all reads of cur done
    }

    u16*   Cb = (u16*)Cv;
    float* Cf = (float*)Cv;
    const float* Rf = (const float*)R;
    const u16*   Rb = (const u16*)R;
    // epilogue: C/D layout col=lane&15, row=(lane>>4)*4+reg  [m89 HW-verified]
    #pragma unroll
    for (int i = 0; i < 4; i++) {
        int mrow = m0 + wm + i * 16 + (l >> 4) * 4;
        #pragma unroll
        for (int j = 0; j < 4; j++) {
            int ncol = n0 + wn + j * 16 + (l & 15);
            if (ncol >= N) continue;
            #pragma unroll
            for (int r = 0; r < 4; r++) {
                int m = mrow + r;
                float v = acc[i][j][r];
                if (MODE == 0) {
                    Cb[(size_t)m * ldc + ncol] = f2b(v);
                } else if (MODE == 1) {
                    v += RF32 ? Rf[(size_t)m * ldR + ncol] : b2f(Rb[(size_t)m * ldR + ncol]);
                    Cb[(size_t)m * ldc + ncol] = f2b(v);
                } else if (MODE == 2) {
                    Cb[(size_t)m * ldc + ncol] = f2b(gelu_exact(v + Rf[ncol]));
                } else {
                    int bb = m / EPAD_;
                    int e = m - bb * EPAD_;
                    if (e < ENC_)
                        Cf[((size_t)bb * P_ + ncol) * ENC_ + e] = v + Rf[ncol];   // f32 OUT
                }
            }
        }
    }
}

// ================= LayerNorm over ENC; input f32 (device) or bf16 (ws); out bf16 ld XLD_ =
template<bool XF32>
__global__ __launch_bounds__(128) void ln_k(const void* __restrict__ xv, int ldin,
                                            const float* __restrict__ w,
                                            const float* __restrict__ b,
                                            u16* __restrict__ y)
{
    int row = blockIdx.x;
    const float* xf = (const float*)xv + (size_t)row * ldin;
    const u16*   xb = (const u16*)xv + (size_t)row * ldin;
    float s = 0.f, q = 0.f;
    for (int c = threadIdx.x; c < ENC_; c += 128) {
        float v = XF32 ? xf[c] : b2f(xb[c]);
        s += v; q += v * v;
    }
    #pragma unroll
    for (int m = 1; m < 64; m <<= 1) { s += __shfl_xor(s, m, 64); q += __shfl_xor(q, m, 64); }
    __shared__ float red[4];
    int wid = threadIdx.x >> 6;
    if ((threadIdx.x & 63) == 0) { red[wid] = s; red[2 + wid] = q; }
    __syncthreads();
    s = red[0] + red[1]; q = red[2] + red[3];
    float mean = s * (1.f / ENC_);
    float var = q * (1.f / ENC_) - mean * mean;
    float rs = rsqrtf(var + 1e-5f);
    u16* yr = y + (size_t)row * XLD_;
    for (int c = threadIdx.x; c < XLD_; c += 128) {
        u16 o = 0;                                   // pad cols 862/863 -> zero
        if (c < ENC_) {
            float v = XF32 ? xf[c] : b2f(xb[c]);
            o = f2b((v - mean) * rs * w[c] + b[c]);
        }
        yr[c] = o;
    }
}

// ================= weight repacks (f32 device inputs -> bf16 ws) =================
__global__ __launch_bounds__(256) void repackT(const float* __restrict__ src, u16* __restrict__ dst,
                                               int Nsrc, int Ksrc, int KP, int total)
{
    int idx = blockIdx.x * 256 + threadIdx.x;
    if (idx >= total) return;
    int n = idx / KP, k = idx - n * KP;
    dst[idx] = (k < Ksrc && n < Nsrc) ? f2b(src[(size_t)k * Nsrc + n]) : (u16)0;
}

__global__ __launch_bounds__(256) void repack_qkvg(const float* __restrict__ wq, const float* __restrict__ wk,
                                                   const float* __restrict__ wv, const float* __restrict__ wg,
                                                   u16* __restrict__ dst)
{
    int idx = blockIdx.x * 256 + threadIdx.x;
    if (idx >= 2048 * KPE_) return;
    int n = idx / KPE_, k = idx - n * KPE_;
    u16 v = 0;
    if (k < ENC_) {
        int sec = n >> 9, c = n & 511;
        if (sec == 3) v = f2b(wg[(size_t)k * DM_ + c]);
        else {
            const float* s = (sec == 0) ? wq : (sec == 1) ? wk : wv;
            int h = c >> 6, d = c & 63;
            v = f2b(s[((size_t)h * ENC_ + k) * HD_ + d]);
        }
    }
    dst[idx] = v;
}

// ================= gate2 (SGLU product, bf16 ws) =================
__global__ __launch_bounds__(256) void gate2_k(const u16* __restrict__ Z, u16* __restrict__ out)
{
    int i = blockIdx.x * 256 + threadIdx.x;
    int row = i >> 6, col = (i & 63) * 8;
    u16x8 a = *(const u16x8*)&Z[(size_t)row * 1024 + col];
    u16x8 b = *(const u16x8*)&Z[(size_t)row * 1024 + 512 + col];
    u16x8 o;
    #pragma unroll
    for (int j = 0; j < 8; j++) o[j] = f2b(b2f(a[j]) * b2f(b[j]));
    *(u16x8*)&out[(size_t)row * 512 + col] = o;
}

// ================= transpose: bufF[B][S][862] bf16 -> XT[B][896][512] =================
__global__ __launch_bounds__(256) void transpose_k(const u16* __restrict__ Xf, u16* __restrict__ XT)
{
    __shared__ u16 t[64][65];
    int b = blockIdx.x, s0 = blockIdx.y * 64, e0 = blockIdx.z * 64;
    int tid = threadIdx.x;
    int sr = tid >> 2, ch = (tid & 3) * 16;
    const u16* src = Xf + ((size_t)(b * S_) + s0 + sr) * ENC_ + e0 + ch;
    #pragma unroll
    for (int i = 0; i < 16; i++)
        t[sr][ch + i] = (e0 + ch + i < ENC_) ? src[i] : (u16)0;
    __syncthreads();
    int er = tid >> 2;
    u16* dst = XT + ((size_t)b * EPAD_ + e0 + er) * 512 + s0 + ch;
    #pragma unroll
    for (int i = 0; i < 16; i++)
        dst[i] = t[ch + i][er];
}

// ================= MFMA retention + GroupNorm + fused swish-gate =================
// grid (S/64, B*H), 256 thr (4 waves). Decay folded into operands:
// gamma^(s-t) = (gamma^(s-s0) Q[s]) . (gamma^(s0-t) K[t]); only diag tile masks s<t.
// Epilogue: GD[srow][c0] = swish(G[srow][c0]) * GroupNorm(Y)[srow][c0]  (gate1 fused)
__global__ __launch_bounds__(256) void retention_k(const u16* __restrict__ QKVG,
                                                   const float* __restrict__ gnw,
                                                   const float* __restrict__ gnb,
                                                   u16* __restrict__ GD)
{
    __shared__ u16 Ks[64 * 72];   // K' rows [t][d], stride 72
    __shared__ u16 Vt[64 * 72];   // V^T [d][t], stride 72
    __shared__ u16 Pl[64 * 72];   // P bf16 [s_rel][t], stride 72 (per-wave rows)
    int tid = threadIdx.x;
    int l = tid & 63, w = tid >> 6;
    int g = l >> 4, fr = l & 15;
    int st = blockIdx.x, bh = blockIdx.y;
    int b = bh >> 3, h = bh & 7;
    int s0 = st * 64;

    const float lo = -3.46573590280f;   // log(1/32)
    const float hi = -6.23832462504f;   // log(1/512)
    float gamma = 1.f - expf(lo + (float)h * ((hi - lo) * (1.f / 7.f)));
    float l2g = log2f(gamma);

    size_t qbase = (size_t)(b * S_) * 2048 + h * 64;

    // ---- Q fragments in registers, scaled by gamma^(s - s0) ----
    int qs_rel = w * 16 + fr;                      // A-frag row = lane&15
    float qscale = exp2f((float)qs_rel * l2g);
    s16x8 qa[2];
    {
        const u16* qsrc = QKVG + qbase + (size_t)(s0 + qs_rel) * 2048;
        #pragma unroll
        for (int ks = 0; ks < 2; ks++) {
            u16x8 raw = *(const u16x8*)(qsrc + ks * 32 + g * 8);
            s16x8 sc;
            #pragma unroll
            for (int e = 0; e < 8; e++) sc[e] = (short)f2b(b2f(raw[e]) * qscale);
            qa[ks] = sc;
        }
    }

    f32x4 accy[4];
    #pragma unroll
    for (int jj = 0; jj < 4; jj++) accy[jj] = (f32x4){0.f, 0.f, 0.f, 0.f};

    int tv = tid >> 2, dv0 = (tid & 3) * 16;       // staging: row tv, 16 cols at dv0

    for (int tt = 0; tt <= st; ++tt) {
        int t0 = tt * 64;
        __syncthreads();                            // prev tile reads done
        {   // stage K' (scaled) row-major + V transposed
            float kscale = exp2f((float)(s0 - (t0 + tv)) * l2g);
            const u16* ksrc = QKVG + qbase + (size_t)(t0 + tv) * 2048 + 512 + dv0;
            const u16* vsrc = QKVG + qbase + (size_t)(t0 + tv) * 2048 + 1024 + dv0;
            u16x8 k0 = *(const u16x8*)ksrc;
            u16x8 k1 = *(const u16x8*)(ksrc + 8);
            s16x8 o0, o1;
            #pragma unroll
            for (int e = 0; e < 8; e++) {
                o0[e] = (short)f2b(b2f(k0[e]) * kscale);
                o1[e] = (short)f2b(b2f(k1[e]) * kscale);
            }
            *(s16x8*)&Ks[tv * 72 + dv0]     = o0;
            *(s16x8*)&Ks[tv * 72 + dv0 + 8] = o1;
            u16x8 v0 = *(const u16x8*)vsrc;
            u16x8 v1 = *(const u16x8*)(vsrc + 8);
            #pragma unroll
            for (int e = 0; e < 8; e++) {
                Vt[(dv0 + e) * 72 + tv]     = v0[e];
                Vt[(dv0 + 8 + e) * 72 + tv] = v1[e];
            }
        }
        __syncthreads();

        // ---- S = Q'K'^T (per wave: 16 rows x 64 t) ----
        f32x4 ps[4];
        #pragma unroll
        for (int j = 0; j < 4; j++) ps[j] = (f32x4){0.f, 0.f, 0.f, 0.f};
        #pragma unroll
        for (int ks = 0; ks < 2; ks++) {
            #pragma unroll
            for (int j = 0; j < 4; j++) {
                s16x8 kf = *(const s16x8*)&Ks[(j * 16 + fr) * 72 + ks * 32 + g * 8];
                ps[j] = __builtin_amdgcn_mfma_f32_16x16x32_bf16(qa[ks], kf, ps[j], 0, 0, 0);
            }
        }
        // ---- mask (diag only) + write P to LDS (bf16) ----
        bool diag = (tt == st);
        #pragma unroll
        for (int j = 0; j < 4; j++) {
            #pragma unroll
            for (int r = 0; r < 4; r++) {
                int srel = w * 16 + g * 4 + r;      // C/D row
                int tloc = j * 16 + fr;             // C/D col
                float p = ps[j][r];
                if (diag && (srel < tloc)) p = 0.f;
                Pl[srel * 72 + tloc] = f2b(p);
            }
        }
        // ---- Y += P V  (A = P rows, B = V^T rows) ----
        s16x8 pa0 = *(const s16x8*)&Pl[(w * 16 + fr) * 72 + g * 8];
        s16x8 pa1 = *(const s16x8*)&Pl[(w * 16 + fr) * 72 + 32 + g * 8];
        #pragma unroll
        for (int jj = 0; jj < 4; jj++) {
            s16x8 vb0 = *(const s16x8*)&Vt[(jj * 16 + fr) * 72 + g * 8];
            s16x8 vb1 = *(const s16x8*)&Vt[(jj * 16 + fr) * 72 + 32 + g * 8];
            accy[jj] = __builtin_amdgcn_mfma_f32_16x16x32_bf16(pa0, vb0, accy[jj], 0, 0, 0);
            accy[jj] = __builtin_amdgcn_mfma_f32_16x16x32_bf16(pa1, vb1, accy[jj], 0, 0, 0);
        }
    }

    // ---- GroupNorm + fused swish gate; row = w*16 + g*4 + r, cols jj*16+fr ----
    #pragma unroll
    for (int r = 0; r < 4; r++) {
        float s_ = accy[0][r] + accy[1][r] + accy[2][r] + accy[3][r];
        float q_ = accy[0][r]*accy[0][r] + accy[1][r]*accy[1][r]
                 + accy[2][r]*accy[2][r] + accy[3][r]*accy[3][r];
        #pragma unroll
        for (int m = 1; m < 16; m <<= 1) { s_ += __shfl_xor(s_, m, 64); q_ += __shfl_xor(q_, m, 64); }
        float mean = s_ * (1.f / 64.f);
        float var = q_ * (1.f / 64.f) - mean * mean;
        float rs = rsqrtf(var + 1e-5f);
        int srow = s0 + w * 16 + g * 4 + r;
        #pragma unroll
        for (int jj = 0; jj < 4; jj++) {
            int c0 = h * 64 + jj * 16 + fr;
            float yn = (accy[jj][r] - mean) * rs * gnw[c0] + gnb[c0];
            float gf = b2f(QKVG[(size_t)(b * S_ + srow) * 2048 + 1536 + c0]);
            GD[(size_t)(b * S_ + srow) * 512 + c0] =
                f2b(gf / (1.f + __expf(-gf)) * yn);
        }
    }
}

// ================= launch =================
extern "C" void kernel_launch(void* const* d_in, const int* in_sizes, int n_in,
                              void* d_out, int out_size, void* d_ws, size_t ws_size,
                              hipStream_t stream)
{
    const float* X    = (const float*)d_in[0];
    const float* wq   = (const float*)d_in[4];
    const float* wk   = (const float*)d_in[5];
    const float* wv   = (const float*)d_in[6];
    const float* wg   = (const float*)d_in[7];
    const float* wo   = (const float*)d_in[8];
    const float* gnw  = (const float*)d_in[9];
    const float* gnb  = (const float*)d_in[10];
    const float* ln1w = (const float*)d_in[11];
    const float* ln1b = (const float*)d_in[12];
    const float* ln2w = (const float*)d_in[13];
    const float* ln2b = (const float*)d_in[14];
    const float* su   = (const float*)d_in[15];
    const float* sv   = (const float*)d_in[16];
    const float* so   = (const float*)d_in[17];
    const float* tw1  = (const float*)d_in[18];
    const float* tb1  = (const float*)d_in[19];
    const float* tw2  = (const float*)d_in[20];
    const float* tb2  = (const float*)d_in[21];
    u16* ws = (u16*)d_ws;

    // ---- ws layout (u16 elements) ----
    const size_t NXE = (size_t)M1_ * ENC_;               // 14,123,008
    const size_t oA  = 0;                                // bufXn [16384][864]
    const size_t oB  = (size_t)M1_ * XLD_ + 1024;        // guard; bufQKVG [16384][2048] / bufZ
    const size_t oC  = oB + (size_t)M1_ * 2048;          // bufYn (now unused; layout kept)
    const size_t oD  = oC + (size_t)M1_ * 512;           // bufGD [16384][512]
    const size_t oE  = oD + (size_t)M1_ * 512;           // bufY [16384][862]
    const size_t oF  = oE + NXE;                         // bufF [16384][862]
    const size_t oW  = oF + NXE;                         // weights arena
    const size_t oWqkvg = oW;                                   // [2048][896]
    const size_t oWo    = oWqkvg + (size_t)2048 * KPE_;         // [896][512]
    const size_t oWsuv  = oWo + (size_t)EPAD_ * 512;            // [1024][896]
    const size_t oWso   = oWsuv + (size_t)1024 * KPE_;          // [896][512]
    const size_t oWt1   = oWso + (size_t)EPAD_ * 512;           // [2048][512]
    const size_t oWt2   = oWt1 + (size_t)2048 * 512;            // [128][2048]
    const size_t END    = oWt2 + (size_t)128 * 2048;            // ~97.7M u16 = 195 MB
    const size_t oXT = 0;                                // post-layers overlay
    const size_t oT1 = (size_t)B_ * EPAD_ * 512;         // post-layers overlay
    if (ws_size < END * sizeof(u16)) return;

    u16* bufXn = ws + oA;
    u16* bufQKVG = ws + oB;
    u16* bufZ = ws + oB;
    u16* bufGD = ws + oD;
    u16* bufY = ws + oE;
    u16* bufF = ws + oF;
    u16* wqkvgT = ws + oWqkvg;
    u16* woT = ws + oWo;
    u16* suvT = ws + oWsuv;
    u16* soT = ws + oWso;
    u16* tw1T = ws + oWt1;
    u16* tw2T = ws + oWt2;
    u16* XT = ws + oXT;
    u16* T1 = ws + oT1;

    dim3 blk(256);
    const size_t NW = (size_t)ENC_ * DM_;

    zgap<<<dim3(4), blk, 0, stream>>>(ws + (size_t)M1_ * XLD_, 1024);

    for (int l = 0; l < L_; ++l) {
        repack_qkvg<<<dim3((2048 * KPE_ + 255) / 256), blk, 0, stream>>>(
            wq + l * NW, wk + l * NW, wv + l * NW, wg + l * NW, wqkvgT);
        repackT<<<dim3((EPAD_ * 512 + 255) / 256), blk, 0, stream>>>(wo + l * NW, woT, ENC_, DM_, 512, EPAD_ * 512);
        repackT<<<dim3((512 * KPE_ + 255) / 256), blk, 0, stream>>>(su + l * NW, suvT, DM_, ENC_, KPE_, 512 * KPE_);
        repackT<<<dim3((512 * KPE_ + 255) / 256), blk, 0, stream>>>(sv + l * NW, suvT + (size_t)512 * KPE_, DM_, ENC_, KPE_, 512 * KPE_);
        repackT<<<dim3((EPAD_ * 512 + 255) / 256), blk, 0, stream>>>(so + l * NW, soT, ENC_, DM_, 512, EPAD_ * 512);

        if (l == 0)
            ln_k<true ><<<dim3(M1_), dim3(128), 0, stream>>>(X,    ENC_, ln1w + l * ENC_, ln1b + l * ENC_, bufXn);
        else
            ln_k<false><<<dim3(M1_), dim3(128), 0, stream>>>(bufF, ENC_, ln1w + l * ENC_, ln1b + l * ENC_, bufXn);

        mgemm<0, false><<<dim3(M1_ / 128, 16), blk, 0, stream>>>(bufXn, XLD_, wqkvgT, KPE_,
                                                                 bufQKVG, 2048, nullptr, 0, M1_, 2048, KPE_);

        retention_k<<<dim3(S_ / 64, B_ * H_), blk, 0, stream>>>(bufQKVG, gnw + l * DM_, gnb + l * DM_, bufGD);

        if (l == 0)
            mgemm<1, true ><<<dim3(M1_ / 128, 7), blk, 0, stream>>>(bufGD, 512, woT, 512,
                                                                    bufY, ENC_, X, ENC_, M1_, ENC_, 512);
        else
            mgemm<1, false><<<dim3(M1_ / 128, 7), blk, 0, stream>>>(bufGD, 512, woT, 512,
                                                                    bufY, ENC_, bufF, ENC_, M1_, ENC_, 512);

        ln_k<false><<<dim3(M1_), dim3(128), 0, stream>>>(bufY, ENC_, ln2w + l * ENC_, ln2b + l * ENC_, bufXn);

        mgemm<0, false><<<dim3(M1_ / 128, 8), blk, 0, stream>>>(bufXn, XLD_, suvT, KPE_,
                                                                bufZ, 1024, nullptr, 0, M1_, 1024, KPE_);

        gate2_k<<<dim3(M1_ * 64 / 256), blk, 0, stream>>>(bufZ, bufGD);

        mgemm<1, false><<<dim3(M1_ / 128, 7), blk, 0, stream>>>(bufGD, 512, soT, 512,
                                                                bufF, ENC_, bufY, ENC_, M1_, ENC_, 512);
    }

    // temporal projection
    repackT<<<dim3((2048 * 512 + 255) / 256), blk, 0, stream>>>(tw1, tw1T, DFF_, S_, 512, 2048 * 512);
    repackT<<<dim3((128 * 2048 + 255) / 256), blk, 0, stream>>>(tw2, tw2T, P_, DFF_, 2048, 128 * 2048);

    transpose_k<<<dim3(B_, S_ / 64, EPAD_ / 64), blk, 0, stream>>>(bufF, XT);

    mgemm<2, false><<<dim3(M2_ / 128, 16), blk, 0, stream>>>(XT, 512, tw1T, 512,
                                                             T1, DFF_, tb1, 0, M2_, DFF_, 512);
    mgemm<3, false><<<dim3(M2_ / 128, 1), blk, 0, stream>>>(T1, DFF_, tw2T, 2048,
                                                            d_out, 0, tb2, 0, M2_, P_, 2048);
}